// Round 5
// baseline (80.637 us; speedup 1.0000x reference)
//
#include <hip/hip_runtime.h>
#include <hip/hip_bf16.h>

// LocationHistoryEncoder: B=256, L=512, N=50000
//   recency[b,n] = max_t { rw^(L-1-t) * valid[b,t] : loc[b,t]==n } (baseline 0)
//   freq[b,n]    = sum_t { valid[b,t] : loc[b,t]==n }
//   out[b,n]     = recency + fw * freq / max(row_max(freq), 1)
//
// 4 blocks per row (1024 blocks x 512 thr). Each block redundantly builds
// the row's LDS hash (O(L) atomics, ~1-2us) but fills + scatters ONLY its
// own 12500-float segment -> fill behaves like the harness's 6.1 TB/s fill
// (many independent blocks; 4 resident/CU keep stores in flight while
// others hash, since __syncthreads drains vmcnt). Segment ownership =>
// no cross-block fill/scatter race; within a block the final barrier
// orders fill stores before scatter stores.

constexpr int kB    = 256;
constexpr int kL    = 512;
constexpr int kN    = 50000;
constexpr int kSegs = 4;               // segments per row
constexpr int kSegN = kN / kSegs;      // 12500 floats, 50000B (16B aligned)
constexpr int kH    = 1024;            // hash slots (pow2, ~2x distinct locs)

__device__ __forceinline__ int hash_loc(int loc) {
    return (int)(((unsigned)loc * 2654435761u) >> 16) & (kH - 1);
}

__global__ __launch_bounds__(kL, 4) void loc_hist_enc_kernel(
    const int* __restrict__ loc_seq,
    const int* __restrict__ mask,
    const float* __restrict__ rw_p,
    const float* __restrict__ fw_p,
    float* __restrict__ out)
{
    const int b   = blockIdx.x >> 2;      // row
    const int seg = blockIdx.x & 3;       // which quarter of the row we own
    const int t   = threadIdx.x;          // == timestep; blockDim.x == kL

    __shared__ int   h_key[kH];           // -1 = empty
    __shared__ int   h_cnt[kH];
    __shared__ int   h_tmin[kH];
    __shared__ int   h_tmax[kH];
    __shared__ float s_pw[kL];            // rw^k
    __shared__ float s_red[kL / 64];
    __shared__ float s_mf;

    const float rw = rw_p[0];
    const float fw = fw_p[0];
    const int   loc = loc_seq[b * kL + t];
    const int   v   = mask[b * kL + t];   // 0 or 1

    // ---- Zero-fill OUR segment first: get stores into flight ASAP.
    // Segment base is 16B-aligned: (b*kN + seg*kSegN)*4 bytes; kSegN*4 % 16 == 0.
    float4* __restrict__ oseg =
        reinterpret_cast<float4*>(out + (size_t)b * kN + (size_t)seg * kSegN);
    const float4 z4 = make_float4(0.f, 0.f, 0.f, 0.f);
    #pragma unroll 4
    for (int i = t; i < kSegN / 4; i += kL) oseg[i] = z4;

    // ---- Init hash + power table (VALU/LDS work overlaps store issue).
    #pragma unroll
    for (int s = t; s < kH; s += kL) {
        h_key[s]  = -1;
        h_cnt[s]  = 0;
        h_tmin[s] = 0x7fffffff;
        h_tmax[s] = -1;
    }
    s_pw[t] = powf(rw, (float)t);

    __syncthreads();                      // hash table initialized

    // ---- O(L) dedup: LDS open-addressing hash.
    if (v) {
        int s = hash_loc(loc);
        while (true) {
            const int k = atomicCAS(&h_key[s], -1, loc);
            if (k == -1 || k == loc) break;
            s = (s + 1) & (kH - 1);
        }
        atomicAdd(&h_cnt[s], 1);
        atomicMin(&h_tmin[s], t);
        atomicMax(&h_tmax[s], t);
    }
    __syncthreads();

    // ---- Row-wide max frequency (empty slots hold 0).
    float mf = fmaxf((float)h_cnt[t], (float)h_cnt[t + kL]);
    #pragma unroll
    for (int off = 32; off >= 1; off >>= 1)
        mf = fmaxf(mf, __shfl_xor(mf, off));
    if ((t & 63) == 0) s_red[t >> 6] = mf;
    __syncthreads();
    if (t == 0) {
        float m = 1.0f;                   // reference clamps max_freq >= 1
        #pragma unroll
        for (int w = 0; w < kL / 64; ++w) m = fmaxf(m, s_red[w]);
        s_mf = m;
    }
    __syncthreads();   // fill stores drained; scatter may now overwrite

    // ---- Scatter keys that fall inside OUR segment (exclusive ownership).
    const int lo = seg * kSegN, hi = lo + kSegN;
    const float mfv = s_mf;
    #pragma unroll
    for (int s = t; s < kH; s += kL) {
        const int key = h_key[s];
        if (key >= lo && key < hi) {
            const float rec = fmaxf(s_pw[kL - 1 - h_tmax[s]],
                                    s_pw[kL - 1 - h_tmin[s]]);
            out[(size_t)b * kN + key] = rec + fw * ((float)h_cnt[s] / mfv);
        }
    }
}

extern "C" void kernel_launch(void* const* d_in, const int* in_sizes, int n_in,
                              void* d_out, int out_size, void* d_ws, size_t ws_size,
                              hipStream_t stream) {
    const int*   loc_seq = (const int*)d_in[0];
    const int*   mask    = (const int*)d_in[1];
    const float* rw      = (const float*)d_in[2];
    const float* fw      = (const float*)d_in[3];
    // d_in[4] = num_locations (compile-time constant kN)
    float* out = (float*)d_out;

    loc_hist_enc_kernel<<<kB * kSegs, kL, 0, stream>>>(loc_seq, mask, rw, fw, out);
}